// Round 1
// baseline (379.147 us; speedup 1.0000x reference)
//
#include <hip/hip_runtime.h>
#include <hip/hip_bf16.h>

// ---------------------------------------------------------------------------
// EnhancedTernaryLinear: out = (x @ W^T) * scale + bias
//   x: [4,2048,4096] f32  -> M=8192, K=4096
//   W: [4096,4096] ternary int8 (harness passes integer inputs as int32)
//   scale, bias: [4096] f32
//   out: [8192,4096] f32
// Plan: convert x -> bf16 (ws), W -> bf16 (ws), then m97-structure bf16
// gemm_bt with MFMA 16x16x32, fused scale/bias epilogue.
// ---------------------------------------------------------------------------

#define M_DIM 8192
#define N_DIM 4096
#define K_DIM 4096
#define BM 128
#define BN 128
#define BK 32

typedef __attribute__((ext_vector_type(8))) short bf16x8; // 8 bf16 in 4 VGPRs
typedef __attribute__((ext_vector_type(4))) float f32x4;

__device__ __forceinline__ unsigned short f2bf(float f) {
  // round-to-nearest-even f32 -> bf16 (inputs are finite normals)
  unsigned int u = __float_as_uint(f);
  unsigned int r = (u + 0x7FFFu + ((u >> 16) & 1u)) >> 16;
  return (unsigned short)r;
}

__device__ __forceinline__ void async16(const void* g, void* l) {
  __builtin_amdgcn_global_load_lds(
      (const __attribute__((address_space(1))) void*)g,
      (__attribute__((address_space(3))) void*)l, 16, 0, 0);
}

// ---------------- conversion kernels ----------------

__global__ void cvt_x_kernel(const float* __restrict__ x,
                             unsigned short* __restrict__ xb, long n) {
  long i0 = ((long)blockIdx.x * blockDim.x + threadIdx.x) * 8;
  long stride = (long)gridDim.x * blockDim.x * 8;
  for (long i = i0; i < n; i += stride) {
    float4 v0 = *(const float4*)(x + i);
    float4 v1 = *(const float4*)(x + i + 4);
    bf16x8 o;
    o[0] = (short)f2bf(v0.x); o[1] = (short)f2bf(v0.y);
    o[2] = (short)f2bf(v0.z); o[3] = (short)f2bf(v0.w);
    o[4] = (short)f2bf(v1.x); o[5] = (short)f2bf(v1.y);
    o[6] = (short)f2bf(v1.z); o[7] = (short)f2bf(v1.w);
    *(bf16x8*)(xb + i) = o;
  }
}

__device__ __forceinline__ unsigned short i2bf(int v) {
  // v in {-1,0,1} -> bf16 bits
  return v == 0 ? (unsigned short)0
                : (v > 0 ? (unsigned short)0x3F80 : (unsigned short)0xBF80);
}

__global__ void cvt_w_kernel(const int* __restrict__ w,
                             unsigned short* __restrict__ wb, long n) {
  long i0 = ((long)blockIdx.x * blockDim.x + threadIdx.x) * 8;
  long stride = (long)gridDim.x * blockDim.x * 8;
  for (long i = i0; i < n; i += stride) {
    int4 a = *(const int4*)(w + i);
    int4 b = *(const int4*)(w + i + 4);
    bf16x8 o;
    o[0] = (short)i2bf(a.x); o[1] = (short)i2bf(a.y);
    o[2] = (short)i2bf(a.z); o[3] = (short)i2bf(a.w);
    o[4] = (short)i2bf(b.x); o[5] = (short)i2bf(b.y);
    o[6] = (short)i2bf(b.z); o[7] = (short)i2bf(b.w);
    *(bf16x8*)(wb + i) = o;
  }
}

// ---------------- MFMA gemm_bt (m97 structure) ----------------
// Tile 128x128, BK=32, 256 threads = 4 waves (2x2), each wave 64x64 =
// 4x4 fragments of 16x16. global_load_lds width-16 staging, 2 barriers/K-step.

__global__ void gemm_bt_kernel(const unsigned short* __restrict__ A, // bf16 [M][K]
                               const unsigned short* __restrict__ B, // bf16 [N][K]
                               const float* __restrict__ scale,
                               const float* __restrict__ bias,
                               float* __restrict__ C) {
  __shared__ unsigned short As[BM * BK]; // [128][32] row-major, 8 KiB
  __shared__ unsigned short Bs[BN * BK];

  const int t = threadIdx.x;
  // XCD-aware swizzle: grid=2048 (divisible by 8), chunk = 256 per XCD
  const int bid = blockIdx.x;
  const int swz = (bid & 7) * ((int)gridDim.x >> 3) + (bid >> 3);
  const int bm = swz >> 5;  // 64 M-tiles
  const int bn = swz & 31;  // 32 N-tiles

  const int wid = t >> 6;
  const int lane = t & 63;
  const int wr = wid >> 1, wc = wid & 1;
  const int fr = lane & 15;  // A-row / B-col within fragment
  const int fq = lane >> 4;  // k-block (8 bf16 each)

  const unsigned short* gA = A + (size_t)bm * BM * K_DIM;
  const unsigned short* gB = B + (size_t)bn * BN * K_DIM;
  const int srow = t >> 2;         // 0..63 staging row
  const int scol = (t & 3) * 8;    // staging col (8 bf16 = 16B)

  f32x4 acc[4][4] = {};

  for (int kt = 0; kt < K_DIM; kt += BK) {
    // stage A,B tiles: LDS dest is lane-linear 16B (global_load_lds constraint)
    async16(gA + (size_t)srow * K_DIM + kt + scol, &As[t * 8]);
    async16(gA + (size_t)(srow + 64) * K_DIM + kt + scol, &As[2048 + t * 8]);
    async16(gB + (size_t)srow * K_DIM + kt + scol, &Bs[t * 8]);
    async16(gB + (size_t)(srow + 64) * K_DIM + kt + scol, &Bs[2048 + t * 8]);
    __syncthreads(); // compiler drains vmcnt(0) before s_barrier

    bf16x8 a[4], b[4];
#pragma unroll
    for (int m = 0; m < 4; ++m)
      a[m] = *(const bf16x8*)&As[(wr * 64 + m * 16 + fr) * BK + fq * 8];
#pragma unroll
    for (int n = 0; n < 4; ++n)
      b[n] = *(const bf16x8*)&Bs[(wc * 64 + n * 16 + fr) * BK + fq * 8];

#pragma unroll
    for (int m = 0; m < 4; ++m)
#pragma unroll
      for (int n = 0; n < 4; ++n)
        acc[m][n] =
            __builtin_amdgcn_mfma_f32_16x16x32_bf16(a[m], b[n], acc[m][n], 0, 0, 0);
    __syncthreads(); // LDS reads done before next overwrite
  }

  // epilogue: C/D layout col=lane&15, row=(lane>>4)*4+j  (m89/m91-verified)
#pragma unroll
  for (int n = 0; n < 4; ++n) {
    const int gc = bn * BN + wc * 64 + n * 16 + fr;
    const float s = scale[gc];
    const float bo = bias[gc];
#pragma unroll
    for (int m = 0; m < 4; ++m) {
      const int gr = bm * BM + wr * 64 + m * 16 + fq * 4;
#pragma unroll
      for (int j = 0; j < 4; ++j)
        C[(size_t)(gr + j) * N_DIM + gc] = acc[m][n][j] * s + bo;
    }
  }
}

// ---------------- naive fallback (only if ws too small) ----------------

__global__ void naive_kernel(const float* __restrict__ x, const int* __restrict__ w,
                             const float* __restrict__ sc, const float* __restrict__ bi,
                             float* __restrict__ out) {
  size_t idx = (size_t)blockIdx.x * blockDim.x + threadIdx.x;
  int m = (int)(idx >> 12);
  int n = (int)(idx & 4095);
  const float* xr = x + (size_t)m * K_DIM;
  const int* wr = w + (size_t)n * K_DIM;
  float acc = 0.f;
  for (int k = 0; k < K_DIM; ++k) acc = fmaf(xr[k], (float)wr[k], acc);
  out[idx] = acc * sc[n] + bi[n];
}

extern "C" void kernel_launch(void* const* d_in, const int* in_sizes, int n_in,
                              void* d_out, int out_size, void* d_ws, size_t ws_size,
                              hipStream_t stream) {
  const float* x = (const float*)d_in[0];
  const int* w = (const int*)d_in[1];        // integer inputs arrive as int32
  const float* scale = (const float*)d_in[2];
  const float* bias = (const float*)d_in[3];
  float* out = (float*)d_out;

  const long nx = (long)M_DIM * K_DIM; // 33,554,432
  const long nw = (long)N_DIM * K_DIM; // 16,777,216
  const size_t need = (size_t)nx * 2 + (size_t)nw * 2; // 96 MiB

  if (ws_size >= need) {
    unsigned short* xb = (unsigned short*)d_ws;
    unsigned short* wb = xb + nx;
    cvt_x_kernel<<<2048, 256, 0, stream>>>(x, xb, nx);
    cvt_w_kernel<<<2048, 256, 0, stream>>>(w, wb, nw);
    gemm_bt_kernel<<<2048, 256, 0, stream>>>(xb, wb, scale, bias, out);
  } else {
    naive_kernel<<<((long)M_DIM * N_DIM) / 256, 256, 0, stream>>>(x, w, scale, bias, out);
  }
}

// Round 2
// 275.565 us; speedup vs baseline: 1.3759x; 1.3759x over previous
//
#include <hip/hip_runtime.h>
#include <hip/hip_bf16.h>

// ---------------------------------------------------------------------------
// EnhancedTernaryLinear: out = (x @ W^T) * scale + bias
// M=8192, N=4096, K=4096. x->bf16, W(ternary)->bf16, then 256x256 8-phase
// MFMA GEMM (T1 XCD-swizzle + T2 LDS XOR-swizzle + T3/T4 counted-vmcnt
// 8-phase + T5 setprio), fused scale/bias epilogue.
// ---------------------------------------------------------------------------

#define M_DIM 8192
#define N_DIM 4096
#define K_DIM 4096
#define BK 64
#define NT (K_DIM / BK)   // 64 K-tiles

typedef __attribute__((ext_vector_type(8))) short bf16x8;
typedef __attribute__((ext_vector_type(4))) float f32x4;

__device__ __forceinline__ unsigned short f2bf(float f) {
  unsigned int u = __float_as_uint(f);
  unsigned int r = (u + 0x7FFFu + ((u >> 16) & 1u)) >> 16;
  return (unsigned short)r;
}

__device__ __forceinline__ void async16(const void* g, void* l) {
  __builtin_amdgcn_global_load_lds(
      (const __attribute__((address_space(1))) void*)g,
      (__attribute__((address_space(3))) void*)l, 16, 0, 0);
}

// ---------------- conversion kernels ----------------

__global__ void cvt_x_kernel(const float* __restrict__ x,
                             unsigned short* __restrict__ xb, long n) {
  long i0 = ((long)blockIdx.x * blockDim.x + threadIdx.x) * 8;
  long stride = (long)gridDim.x * blockDim.x * 8;
  for (long i = i0; i < n; i += stride) {
    float4 v0 = *(const float4*)(x + i);
    float4 v1 = *(const float4*)(x + i + 4);
    bf16x8 o;
    o[0] = (short)f2bf(v0.x); o[1] = (short)f2bf(v0.y);
    o[2] = (short)f2bf(v0.z); o[3] = (short)f2bf(v0.w);
    o[4] = (short)f2bf(v1.x); o[5] = (short)f2bf(v1.y);
    o[6] = (short)f2bf(v1.z); o[7] = (short)f2bf(v1.w);
    *(bf16x8*)(xb + i) = o;
  }
}

__device__ __forceinline__ unsigned short i2bf(int v) {
  return v == 0 ? (unsigned short)0
                : (v > 0 ? (unsigned short)0x3F80 : (unsigned short)0xBF80);
}

__global__ void cvt_w_kernel(const int* __restrict__ w,
                             unsigned short* __restrict__ wb, long n) {
  long i0 = ((long)blockIdx.x * blockDim.x + threadIdx.x) * 8;
  long stride = (long)gridDim.x * blockDim.x * 8;
  for (long i = i0; i < n; i += stride) {
    int4 a = *(const int4*)(w + i);
    int4 b = *(const int4*)(w + i + 4);
    bf16x8 o;
    o[0] = (short)i2bf(a.x); o[1] = (short)i2bf(a.y);
    o[2] = (short)i2bf(a.z); o[3] = (short)i2bf(a.w);
    o[4] = (short)i2bf(b.x); o[5] = (short)i2bf(b.y);
    o[6] = (short)i2bf(b.z); o[7] = (short)i2bf(b.w);
    *(bf16x8*)(wb + i) = o;
  }
}

// ---------------- 256x256 8-phase GEMM ----------------
// 512 threads = 8 waves (2 wr x 4 wc). Per-wave output 128x64 = 8x4 frags.
// LDS (ushort offsets), 128 KiB total:
//   A region (buf,mh): buf*32768 + mh*8192      -- 128 rows x 64 cols bf16
//     region row rho in [0,128): global tile row r = (rho>>6)*128 + mh*64 + (rho&63)
//   B region (buf,nh): buf*32768 + 16384 + nh*8192
//     region row rho: global tile col c = (rho>>5)*64 + nh*32 + (rho&31)
// Swizzle: LDS[rho][colb ^ ((rho&7)<<4)] holds logical [rho][colb]; staged by
// inverse-swizzling the GLOBAL source (linear LDS dest, rule #21).
// Phase order per tile: q0(mh0,nh0) q1(mh0,nh1) q2(mh1,nh1) q3(mh1,nh0).
// Staging: q0 -> B-nh0 of T+1; q1 -> A-mh0 of T+2; q2 -> B-nh1 of T+2;
//          q3 -> A-mh1 of T+2. Every stage lands in a region whose last
//          ds_read finished a barrier earlier. vmcnt(6) at q3 retires T+1.

#define AOFF(b, mh) ((b)*32768 + (mh)*8192)
#define BOFF(b, nh) ((b)*32768 + 16384 + (nh)*8192)

__device__ __forceinline__ void stage_A_half(const unsigned short* __restrict__ A,
                                             int grow0, int ktE, int mh,
                                             unsigned short* lds_region, int t) {
  const int colb = (t & 7) * 16;
  const int swz = ((t >> 3) & 7) << 4;
  const int scol = (colb ^ swz) >> 1;  // element offset in row
#pragma unroll
  for (int rr = 0; rr < 2; ++rr) {
    int rho = rr * 64 + (t >> 3);
    int r = ((rho >> 6) << 7) + mh * 64 + (rho & 63);
    async16(A + (size_t)(grow0 + r) * K_DIM + ktE + scol,
            lds_region + rr * 4096 + t * 8);
  }
}

__device__ __forceinline__ void stage_B_half(const unsigned short* __restrict__ B,
                                             int gcol0, int ktE, int nh,
                                             unsigned short* lds_region, int t) {
  const int colb = (t & 7) * 16;
  const int swz = ((t >> 3) & 7) << 4;
  const int scol = (colb ^ swz) >> 1;
#pragma unroll
  for (int rr = 0; rr < 2; ++rr) {
    int rho = rr * 64 + (t >> 3);
    int c = ((rho >> 5) << 6) + nh * 32 + (rho & 31);
    async16(B + (size_t)(gcol0 + c) * K_DIM + ktE + scol,
            lds_region + rr * 4096 + t * 8);
  }
}

__device__ __forceinline__ void load_a(const unsigned short* reg_base, int wr,
                                       int fr, int e0, bf16x8 aF[4][2]) {
#pragma unroll
  for (int mi = 0; mi < 4; ++mi) {
    const unsigned short* p = reg_base + (wr * 64 + mi * 16 + fr) * 64;
    aF[mi][0] = *(const bf16x8*)(p + e0);
    aF[mi][1] = *(const bf16x8*)(p + (e0 ^ 32));
  }
}

__device__ __forceinline__ void load_b(const unsigned short* reg_base, int wc,
                                       int fr, int e0, bf16x8 bF[2][2]) {
#pragma unroll
  for (int ni = 0; ni < 2; ++ni) {
    const unsigned short* p = reg_base + (wc * 32 + ni * 16 + fr) * 64;
    bF[ni][0] = *(const bf16x8*)(p + e0);
    bF[ni][1] = *(const bf16x8*)(p + (e0 ^ 32));
  }
}

#define MFMA_QUAD(MH, NH)                                                      \
  do {                                                                         \
    __builtin_amdgcn_s_setprio(1);                                             \
    _Pragma("unroll") for (int mi = 0; mi < 4; ++mi)                           \
    _Pragma("unroll") for (int ni = 0; ni < 2; ++ni)                           \
    _Pragma("unroll") for (int kk = 0; kk < 2; ++kk)                           \
      acc[(MH)*4 + mi][(NH)*2 + ni] = __builtin_amdgcn_mfma_f32_16x16x32_bf16( \
          aF[mi][kk], bF[ni][kk], acc[(MH)*4 + mi][(NH)*2 + ni], 0, 0, 0);     \
    __builtin_amdgcn_s_setprio(0);                                             \
  } while (0)

#define PHASE_SYNC()                                      \
  __builtin_amdgcn_s_barrier();                           \
  asm volatile("s_waitcnt lgkmcnt(0)" ::: "memory")

__global__ void __launch_bounds__(512, 2)
gemm_bt_kernel(const unsigned short* __restrict__ A,  // bf16 [M][K]
               const unsigned short* __restrict__ B,  // bf16 [N][K]
               const float* __restrict__ scale, const float* __restrict__ bias,
               float* __restrict__ C) {
  __shared__ unsigned short lds[65536];  // 128 KiB

  const int t = threadIdx.x;
  // XCD-aware swizzle: 512 wgs, 64 per XCD
  const int bid = blockIdx.x;
  const int swz = (bid & 7) * 64 + (bid >> 3);
  const int bm = swz >> 4;  // 32 M-tiles
  const int bn = swz & 15;  // 16 N-tiles
  const int brow = bm * 256, bcol = bn * 256;

  const int wid = t >> 6, lane = t & 63;
  const int wr = wid >> 2, wc = wid & 3;
  const int fr = lane & 15, fq = lane >> 4;
  const int e0 = ((fq * 16) ^ ((fr & 7) << 4)) >> 1;  // kk=0 read offset (elems)

  f32x4 acc[8][4] = {};
  bf16x8 aF[4][2], bF[2][2];

  // ---- prologue: tile0 all 4 halves + tile1 first 3 (order matters) ----
  stage_A_half(A, brow, 0, 0, lds + AOFF(0, 0), t);
  stage_B_half(B, bcol, 0, 1, lds + BOFF(0, 1), t);
  stage_A_half(A, brow, 0, 1, lds + AOFF(0, 1), t);
  stage_B_half(B, bcol, 0, 0, lds + BOFF(0, 0), t);
  stage_A_half(A, brow, BK, 0, lds + AOFF(1, 0), t);
  stage_B_half(B, bcol, BK, 1, lds + BOFF(1, 1), t);
  stage_A_half(A, brow, BK, 1, lds + AOFF(1, 1), t);
  asm volatile("s_waitcnt vmcnt(6)" ::: "memory");  // tile0 landed
  __builtin_amdgcn_s_barrier();

  for (int T = 0; T < NT; ++T) {
    const int b = T & 1;
    const int kN1 = (T + 1) * BK, kN2 = (T + 2) * BK;

    // -- q0 (mh0,nh0)
    load_a(lds + AOFF(b, 0), wr, fr, e0, aF);
    load_b(lds + BOFF(b, 0), wc, fr, e0, bF);
    if (T + 1 < NT) stage_B_half(B, bcol, kN1, 0, lds + BOFF(b ^ 1, 0), t);
    PHASE_SYNC();
    MFMA_QUAD(0, 0);
    __builtin_amdgcn_s_barrier();

    // -- q1 (mh0,nh1)
    load_b(lds + BOFF(b, 1), wc, fr, e0, bF);
    if (T + 2 < NT) stage_A_half(A, brow, kN2, 0, lds + AOFF(b, 0), t);
    PHASE_SYNC();
    MFMA_QUAD(0, 1);
    __builtin_amdgcn_s_barrier();

    // -- q2 (mh1,nh1)
    load_a(lds + AOFF(b, 1), wr, fr, e0, aF);
    if (T + 2 < NT) stage_B_half(B, bcol, kN2, 1, lds + BOFF(b, 1), t);
    PHASE_SYNC();
    MFMA_QUAD(1, 1);
    __builtin_amdgcn_s_barrier();

    // -- q3 (mh1,nh0)
    load_b(lds + BOFF(b, 0), wc, fr, e0, bF);
    if (T + 2 < NT) stage_A_half(A, brow, kN2, 1, lds + AOFF(b, 1), t);
    PHASE_SYNC();
    MFMA_QUAD(1, 0);
    if (T < NT - 2)
      asm volatile("s_waitcnt vmcnt(6)" ::: "memory");  // next tile landed
    else if (T == NT - 2)
      asm volatile("s_waitcnt vmcnt(0)" ::: "memory");  // final drain
    __builtin_amdgcn_s_barrier();
  }

  // ---- epilogue: scale/bias, C/D layout col=lane&15, row=(lane>>4)*4+j ----
#pragma unroll
  for (int n = 0; n < 4; ++n) {
    const int gc = bcol + wc * 64 + n * 16 + fr;
    const float s = scale[gc];
    const float bo = bias[gc];
#pragma unroll
    for (int m = 0; m < 8; ++m) {
      const int gr = brow + wr * 128 + m * 16 + fq * 4;
#pragma unroll
      for (int j = 0; j < 4; ++j)
        C[(size_t)(gr + j) * N_DIM + gc] = acc[m][n][j] * s + bo;
    }
  }
}

// ---------------- naive fallback (only if ws too small) ----------------

__global__ void naive_kernel(const float* __restrict__ x, const int* __restrict__ w,
                             const float* __restrict__ sc, const float* __restrict__ bi,
                             float* __restrict__ out) {
  size_t idx = (size_t)blockIdx.x * blockDim.x + threadIdx.x;
  int m = (int)(idx >> 12);
  int n = (int)(idx & 4095);
  const float* xr = x + (size_t)m * K_DIM;
  const int* wr = w + (size_t)n * K_DIM;
  float acc = 0.f;
  for (int k = 0; k < K_DIM; ++k) acc = fmaf(xr[k], (float)wr[k], acc);
  out[idx] = acc * sc[n] + bi[n];
}

extern "C" void kernel_launch(void* const* d_in, const int* in_sizes, int n_in,
                              void* d_out, int out_size, void* d_ws, size_t ws_size,
                              hipStream_t stream) {
  const float* x = (const float*)d_in[0];
  const int* w = (const int*)d_in[1];
  const float* scale = (const float*)d_in[2];
  const float* bias = (const float*)d_in[3];
  float* out = (float*)d_out;

  const long nx = (long)M_DIM * K_DIM;
  const long nw = (long)N_DIM * K_DIM;
  const size_t need = (size_t)nx * 2 + (size_t)nw * 2;  // 96 MiB

  if (ws_size >= need) {
    unsigned short* xb = (unsigned short*)d_ws;
    unsigned short* wb = xb + nx;
    cvt_x_kernel<<<2048, 256, 0, stream>>>(x, xb, nx);
    cvt_w_kernel<<<2048, 256, 0, stream>>>(w, wb, nw);
    gemm_bt_kernel<<<512, 512, 0, stream>>>(xb, wb, scale, bias, out);
  } else {
    naive_kernel<<<((long)M_DIM * N_DIM) / 256, 256, 0, stream>>>(x, w, scale, bias, out);
  }
}

// Round 3
// 270.976 us; speedup vs baseline: 1.3992x; 1.0169x over previous
//
#include <hip/hip_runtime.h>
#include <hip/hip_bf16.h>

// ---------------------------------------------------------------------------
// EnhancedTernaryLinear: out = (x @ W^T) * scale + bias
// M=8192, N=4096, K=4096. x->bf16, W(ternary)->bf16, then 256x256 8-phase
// MFMA GEMM (T1 XCD-swizzle + T2 LDS XOR-swizzle + T3/T4 counted-vmcnt +
// T5 setprio), kk-OUTER MFMA ordering (no acc-chain issue bubbles),
// bF register double-buffer (24 ds_read/K-tile), fused scale/bias epilogue.
// ---------------------------------------------------------------------------

#define M_DIM 8192
#define N_DIM 4096
#define K_DIM 4096
#define BK 64
#define NT (K_DIM / BK)   // 64 K-tiles

typedef __attribute__((ext_vector_type(8))) short bf16x8;
typedef __attribute__((ext_vector_type(4))) float f32x4;

__device__ __forceinline__ unsigned short f2bf(float f) {
  unsigned int u = __float_as_uint(f);
  unsigned int r = (u + 0x7FFFu + ((u >> 16) & 1u)) >> 16;
  return (unsigned short)r;
}

__device__ __forceinline__ void async16(const void* g, void* l) {
  __builtin_amdgcn_global_load_lds(
      (const __attribute__((address_space(1))) void*)g,
      (__attribute__((address_space(3))) void*)l, 16, 0, 0);
}

// ---------------- conversion kernels ----------------

__global__ void cvt_x_kernel(const float* __restrict__ x,
                             unsigned short* __restrict__ xb, long n) {
  long i0 = ((long)blockIdx.x * blockDim.x + threadIdx.x) * 8;
  long stride = (long)gridDim.x * blockDim.x * 8;
  for (long i = i0; i < n; i += stride) {
    float4 v0 = *(const float4*)(x + i);
    float4 v1 = *(const float4*)(x + i + 4);
    bf16x8 o;
    o[0] = (short)f2bf(v0.x); o[1] = (short)f2bf(v0.y);
    o[2] = (short)f2bf(v0.z); o[3] = (short)f2bf(v0.w);
    o[4] = (short)f2bf(v1.x); o[5] = (short)f2bf(v1.y);
    o[6] = (short)f2bf(v1.z); o[7] = (short)f2bf(v1.w);
    *(bf16x8*)(xb + i) = o;
  }
}

__device__ __forceinline__ unsigned short i2bf(int v) {
  return v == 0 ? (unsigned short)0
                : (v > 0 ? (unsigned short)0x3F80 : (unsigned short)0xBF80);
}

__global__ void cvt_w_kernel(const int* __restrict__ w,
                             unsigned short* __restrict__ wb, long n) {
  long i0 = ((long)blockIdx.x * blockDim.x + threadIdx.x) * 8;
  long stride = (long)gridDim.x * blockDim.x * 8;
  for (long i = i0; i < n; i += stride) {
    int4 a = *(const int4*)(w + i);
    int4 b = *(const int4*)(w + i + 4);
    bf16x8 o;
    o[0] = (short)i2bf(a.x); o[1] = (short)i2bf(a.y);
    o[2] = (short)i2bf(a.z); o[3] = (short)i2bf(a.w);
    o[4] = (short)i2bf(b.x); o[5] = (short)i2bf(b.y);
    o[6] = (short)i2bf(b.z); o[7] = (short)i2bf(b.w);
    *(bf16x8*)(wb + i) = o;
  }
}

// ---------------- 256x256 8-phase GEMM ----------------
// 512 threads = 8 waves (2 wr x 4 wc). Per-wave output 128x64 = 8x4 frags.
// LDS regions (ushort offsets), 128 KiB:
//   A (buf,mh): buf*32768 + mh*8192        (128 rows x 64 cols bf16)
//   B (buf,nh): buf*32768 + 16384 + nh*8192
// Swizzle: LDS[rho][colb ^ ((rho&7)<<4)]; staged via inverse-swizzled GLOBAL
// source + linear LDS dest (rule #21), read with swizzled offset.
// Phases per tile T (buf b): q0(mh0,nh0) q1(mh0,nh1) q2(mh1,nh1) q3(mh1,nh0).
// Register frags: aF reloaded at q0/q2; bF0 (nh0) loaded q0, reused q3;
// bF1 (nh1) loaded q1, reused q2 -> q3 has ZERO ds_reads.
// Stages: q0 -> B-nh0(T+1); q1 -> A-mh0(T+2); q2 -> B-nh1(T+2);
//         q3 -> A-mh1(T+2). vmcnt(6) at q3 retires exactly tile T+1.

#define AOFF(b, mh) ((b)*32768 + (mh)*8192)
#define BOFF(b, nh) ((b)*32768 + 16384 + (nh)*8192)

__device__ __forceinline__ void stage_A_half(const unsigned short* __restrict__ A,
                                             int grow0, int ktE, int mh,
                                             unsigned short* lds_region, int t) {
  const int colb = (t & 7) * 16;
  const int swz = ((t >> 3) & 7) << 4;
  const int scol = (colb ^ swz) >> 1;
#pragma unroll
  for (int rr = 0; rr < 2; ++rr) {
    int rho = rr * 64 + (t >> 3);
    int r = ((rho >> 6) << 7) + mh * 64 + (rho & 63);
    async16(A + (size_t)(grow0 + r) * K_DIM + ktE + scol,
            lds_region + rr * 4096 + t * 8);
  }
}

__device__ __forceinline__ void stage_B_half(const unsigned short* __restrict__ B,
                                             int gcol0, int ktE, int nh,
                                             unsigned short* lds_region, int t) {
  const int colb = (t & 7) * 16;
  const int swz = ((t >> 3) & 7) << 4;
  const int scol = (colb ^ swz) >> 1;
#pragma unroll
  for (int rr = 0; rr < 2; ++rr) {
    int rho = rr * 64 + (t >> 3);
    int c = ((rho >> 5) << 6) + nh * 32 + (rho & 31);
    async16(B + (size_t)(gcol0 + c) * K_DIM + ktE + scol,
            lds_region + rr * 4096 + t * 8);
  }
}

__device__ __forceinline__ void load_a(const unsigned short* reg_base, int wr,
                                       int fr, int e0, bf16x8 aF[4][2]) {
#pragma unroll
  for (int mi = 0; mi < 4; ++mi) {
    const unsigned short* p = reg_base + (wr * 64 + mi * 16 + fr) * 64;
    aF[mi][0] = *(const bf16x8*)(p + e0);
    aF[mi][1] = *(const bf16x8*)(p + (e0 ^ 32));
  }
}

__device__ __forceinline__ void load_b(const unsigned short* reg_base, int wc,
                                       int fr, int e0, bf16x8 bF[2][2]) {
#pragma unroll
  for (int ni = 0; ni < 2; ++ni) {
    const unsigned short* p = reg_base + (wc * 32 + ni * 16 + fr) * 64;
    bF[ni][0] = *(const bf16x8*)(p + e0);
    bF[ni][1] = *(const bf16x8*)(p + (e0 ^ 32));
  }
}

// kk-OUTER: 8 independent MFMAs (distinct acc) per kk group -> no issue
// bubbles from acc chaining; the kk=1 group lands 8 issue slots behind its
// producers, past MFMA latency.
#define MFMA_QUAD(MH, NH, BF)                                                  \
  do {                                                                         \
    __builtin_amdgcn_s_setprio(1);                                             \
    _Pragma("unroll") for (int kk = 0; kk < 2; ++kk)                           \
    _Pragma("unroll") for (int mi = 0; mi < 4; ++mi)                           \
    _Pragma("unroll") for (int ni = 0; ni < 2; ++ni)                           \
      acc[(MH)*4 + mi][(NH)*2 + ni] = __builtin_amdgcn_mfma_f32_16x16x32_bf16( \
          aF[mi][kk], BF[ni][kk], acc[(MH)*4 + mi][(NH)*2 + ni], 0, 0, 0);     \
    __builtin_amdgcn_s_setprio(0);                                             \
  } while (0)

#define PHASE_SYNC()                                      \
  __builtin_amdgcn_s_barrier();                           \
  asm volatile("s_waitcnt lgkmcnt(0)" ::: "memory")

__global__ void __launch_bounds__(512, 2)
gemm_bt_kernel(const unsigned short* __restrict__ A,  // bf16 [M][K]
               const unsigned short* __restrict__ B,  // bf16 [N][K]
               const float* __restrict__ scale, const float* __restrict__ bias,
               float* __restrict__ C) {
  __shared__ unsigned short lds[65536];  // 128 KiB

  const int t = threadIdx.x;
  const int bid = blockIdx.x;
  const int swz = (bid & 7) * 64 + (bid >> 3);  // 512 wgs, 64/XCD (bijective)
  const int bm = swz >> 4;  // 32 M-tiles
  const int bn = swz & 15;  // 16 N-tiles
  const int brow = bm * 256, bcol = bn * 256;

  const int wid = t >> 6, lane = t & 63;
  const int wr = wid >> 2, wc = wid & 3;
  const int fr = lane & 15, fq = lane >> 4;
  const int e0 = ((fq * 16) ^ ((fr & 7) << 4)) >> 1;  // kk=0 read offset

  f32x4 acc[8][4] = {};
  bf16x8 aF[4][2], bF0[2][2], bF1[2][2];

  // ---- prologue: tile0 all 4 halves + tile1's {A-mh0, B-nh1, A-mh1} ----
  stage_A_half(A, brow, 0, 0, lds + AOFF(0, 0), t);
  stage_B_half(B, bcol, 0, 1, lds + BOFF(0, 1), t);
  stage_A_half(A, brow, 0, 1, lds + AOFF(0, 1), t);
  stage_B_half(B, bcol, 0, 0, lds + BOFF(0, 0), t);
  stage_A_half(A, brow, BK, 0, lds + AOFF(1, 0), t);
  stage_B_half(B, bcol, BK, 1, lds + BOFF(1, 1), t);
  stage_A_half(A, brow, BK, 1, lds + AOFF(1, 1), t);
  asm volatile("s_waitcnt vmcnt(6)" ::: "memory");  // tile0 landed
  __builtin_amdgcn_s_barrier();

  for (int T = 0; T < NT; ++T) {
    const int b = T & 1;
    const int kN1 = (T + 1) * BK, kN2 = (T + 2) * BK;

    // -- q0 (mh0,nh0): 12 ds_reads
    load_a(lds + AOFF(b, 0), wr, fr, e0, aF);
    load_b(lds + BOFF(b, 0), wc, fr, e0, bF0);
    if (T + 1 < NT) stage_B_half(B, bcol, kN1, 0, lds + BOFF(b ^ 1, 0), t);
    asm volatile("s_waitcnt lgkmcnt(8)" ::: "memory");
    PHASE_SYNC();
    MFMA_QUAD(0, 0, bF0);
    __builtin_amdgcn_s_barrier();

    // -- q1 (mh0,nh1): 4 ds_reads
    load_b(lds + BOFF(b, 1), wc, fr, e0, bF1);
    if (T + 2 < NT) stage_A_half(A, brow, kN2, 0, lds + AOFF(b, 0), t);
    PHASE_SYNC();
    MFMA_QUAD(0, 1, bF1);
    __builtin_amdgcn_s_barrier();

    // -- q2 (mh1,nh1): 8 ds_reads (bF1 reused in regs)
    load_a(lds + AOFF(b, 1), wr, fr, e0, aF);
    if (T + 2 < NT) stage_B_half(B, bcol, kN2, 1, lds + BOFF(b, 1), t);
    PHASE_SYNC();
    MFMA_QUAD(1, 1, bF1);
    __builtin_amdgcn_s_barrier();

    // -- q3 (mh1,nh0): 0 ds_reads (aF from q2, bF0 from q0)
    if (T + 2 < NT) stage_A_half(A, brow, kN2, 1, lds + AOFF(b, 1), t);
    PHASE_SYNC();
    MFMA_QUAD(1, 0, bF0);
    if (T < NT - 2)
      asm volatile("s_waitcnt vmcnt(6)" ::: "memory");  // tile T+1 landed
    else if (T == NT - 2)
      asm volatile("s_waitcnt vmcnt(0)" ::: "memory");  // final drain
    __builtin_amdgcn_s_barrier();
  }

  // ---- epilogue: scale/bias, C/D layout col=lane&15, row=(lane>>4)*4+j ----
#pragma unroll
  for (int n = 0; n < 4; ++n) {
    const int gc = bcol + wc * 64 + n * 16 + fr;
    const float s = scale[gc];
    const float bo = bias[gc];
#pragma unroll
    for (int m = 0; m < 8; ++m) {
      const int gr = brow + wr * 128 + m * 16 + fq * 4;
#pragma unroll
      for (int j = 0; j < 4; ++j)
        C[(size_t)(gr + j) * N_DIM + gc] = acc[m][n][j] * s + bo;
    }
  }
}

// ---------------- naive fallback (only if ws too small) ----------------

__global__ void naive_kernel(const float* __restrict__ x, const int* __restrict__ w,
                             const float* __restrict__ sc, const float* __restrict__ bi,
                             float* __restrict__ out) {
  size_t idx = (size_t)blockIdx.x * blockDim.x + threadIdx.x;
  int m = (int)(idx >> 12);
  int n = (int)(idx & 4095);
  const float* xr = x + (size_t)m * K_DIM;
  const int* wr = w + (size_t)n * K_DIM;
  float acc = 0.f;
  for (int k = 0; k < K_DIM; ++k) acc = fmaf(xr[k], (float)wr[k], acc);
  out[idx] = acc * sc[n] + bi[n];
}

extern "C" void kernel_launch(void* const* d_in, const int* in_sizes, int n_in,
                              void* d_out, int out_size, void* d_ws, size_t ws_size,
                              hipStream_t stream) {
  const float* x = (const float*)d_in[0];
  const int* w = (const int*)d_in[1];
  const float* scale = (const float*)d_in[2];
  const float* bias = (const float*)d_in[3];
  float* out = (float*)d_out;

  const long nx = (long)M_DIM * K_DIM;
  const long nw = (long)N_DIM * K_DIM;
  const size_t need = (size_t)nx * 2 + (size_t)nw * 2;  // 96 MiB

  if (ws_size >= need) {
    unsigned short* xb = (unsigned short*)d_ws;
    unsigned short* wb = xb + nx;
    cvt_x_kernel<<<2048, 256, 0, stream>>>(x, xb, nx);
    cvt_w_kernel<<<2048, 256, 0, stream>>>(w, wb, nw);
    gemm_bt_kernel<<<512, 512, 0, stream>>>(xb, wb, scale, bias, out);
  } else {
    naive_kernel<<<((long)M_DIM * N_DIM) / 256, 256, 0, stream>>>(x, w, scale, bias, out);
  }
}

// Round 4
// 269.733 us; speedup vs baseline: 1.4056x; 1.0046x over previous
//
#include <hip/hip_runtime.h>
#include <hip/hip_bf16.h>

// ---------------------------------------------------------------------------
// EnhancedTernaryLinear: out = (x @ W^T) * scale + bias
// M=8192, N=4096, K=4096. x->bf16, W(ternary)->bf16, then 256x256 8-phase
// MFMA GEMM. R4: balanced ds_read distribution (8,4,8,4) via q3 post-MFMA
// preload of next tile's bF0; vmcnt(4) moved to q2-end. Register-neutral.
// ---------------------------------------------------------------------------

#define M_DIM 8192
#define N_DIM 4096
#define K_DIM 4096
#define BK 64
#define NT (K_DIM / BK)   // 64 K-tiles

typedef __attribute__((ext_vector_type(8))) short bf16x8;
typedef __attribute__((ext_vector_type(4))) float f32x4;

__device__ __forceinline__ unsigned short f2bf(float f) {
  unsigned int u = __float_as_uint(f);
  unsigned int r = (u + 0x7FFFu + ((u >> 16) & 1u)) >> 16;
  return (unsigned short)r;
}

__device__ __forceinline__ void async16(const void* g, void* l) {
  __builtin_amdgcn_global_load_lds(
      (const __attribute__((address_space(1))) void*)g,
      (__attribute__((address_space(3))) void*)l, 16, 0, 0);
}

// ---------------- conversion kernels ----------------

__global__ void cvt_x_kernel(const float* __restrict__ x,
                             unsigned short* __restrict__ xb, long n) {
  long i0 = ((long)blockIdx.x * blockDim.x + threadIdx.x) * 8;
  long stride = (long)gridDim.x * blockDim.x * 8;
  for (long i = i0; i < n; i += stride) {
    float4 v0 = *(const float4*)(x + i);
    float4 v1 = *(const float4*)(x + i + 4);
    bf16x8 o;
    o[0] = (short)f2bf(v0.x); o[1] = (short)f2bf(v0.y);
    o[2] = (short)f2bf(v0.z); o[3] = (short)f2bf(v0.w);
    o[4] = (short)f2bf(v1.x); o[5] = (short)f2bf(v1.y);
    o[6] = (short)f2bf(v1.z); o[7] = (short)f2bf(v1.w);
    *(bf16x8*)(xb + i) = o;
  }
}

__device__ __forceinline__ unsigned short i2bf(int v) {
  return v == 0 ? (unsigned short)0
                : (v > 0 ? (unsigned short)0x3F80 : (unsigned short)0xBF80);
}

__global__ void cvt_w_kernel(const int* __restrict__ w,
                             unsigned short* __restrict__ wb, long n) {
  long i0 = ((long)blockIdx.x * blockDim.x + threadIdx.x) * 8;
  long stride = (long)gridDim.x * blockDim.x * 8;
  for (long i = i0; i < n; i += stride) {
    int4 a = *(const int4*)(w + i);
    int4 b = *(const int4*)(w + i + 4);
    bf16x8 o;
    o[0] = (short)i2bf(a.x); o[1] = (short)i2bf(a.y);
    o[2] = (short)i2bf(a.z); o[3] = (short)i2bf(a.w);
    o[4] = (short)i2bf(b.x); o[5] = (short)i2bf(b.y);
    o[6] = (short)i2bf(b.z); o[7] = (short)i2bf(b.w);
    *(bf16x8*)(wb + i) = o;
  }
}

// ---------------- 256x256 8-phase GEMM ----------------
// 512 threads = 8 waves (2 wr x 4 wc). Per-wave output 128x64 = 8x4 frags.
// LDS regions (ushort offsets), 128 KiB:
//   A (buf,mh): buf*32768 + mh*8192        (128 rows x 64 cols bf16)
//   B (buf,nh): buf*32768 + 16384 + nh*8192
// Swizzle: LDS[rho][colb ^ ((rho&7)<<4)]; staged via inverse-swizzled GLOBAL
// source + linear LDS dest, read with swizzled offset. 0 bank conflicts (R2).
//
// Phases per tile T (buf b): q0(mh0,nh0) q1(mh0,nh1) q2(mh1,nh1) q3(mh1,nh0).
// BALANCED ds_read distribution (8,4,8,4):
//   q0: aF0 (8)            [bF0 preloaded at q3(T-1), post-MFMA]
//   q1: bF1 (4)
//   q2: aF1 (8)            [bF1 reused in regs]
//   q3: 0 before MFMA; AFTER MFMA: preload bF0' of T+1 (4)  <- post-last-use
//       of old bF0 => compiler reuses regs, no ping-pong, VGPR unchanged.
// Stages: q0 -> B-nh0(T+1); q1 -> A-mh0(T+2); q2 -> B-nh1(T+2);
//         q3 -> A-mh1(T+2).
// vmcnt(4) at q2-end (outstanding = q1,q2 stages) retires through q0(T)'s
// B-nh0(T+1) stage => q3's preload of that region is race-free; barrier at
// q2-end makes it cross-wave visible. In-flight never drains to 0 except the
// single vmcnt(0) at T==NT-2.

#define AOFF(b, mh) ((b)*32768 + (mh)*8192)
#define BOFF(b, nh) ((b)*32768 + 16384 + (nh)*8192)

__device__ __forceinline__ void stage_A_half(const unsigned short* __restrict__ A,
                                             int grow0, int ktE, int mh,
                                             unsigned short* lds_region, int t) {
  const int colb = (t & 7) * 16;
  const int swz = ((t >> 3) & 7) << 4;
  const int scol = (colb ^ swz) >> 1;
#pragma unroll
  for (int rr = 0; rr < 2; ++rr) {
    int rho = rr * 64 + (t >> 3);
    int r = ((rho >> 6) << 7) + mh * 64 + (rho & 63);
    async16(A + (size_t)(grow0 + r) * K_DIM + ktE + scol,
            lds_region + rr * 4096 + t * 8);
  }
}

__device__ __forceinline__ void stage_B_half(const unsigned short* __restrict__ B,
                                             int gcol0, int ktE, int nh,
                                             unsigned short* lds_region, int t) {
  const int colb = (t & 7) * 16;
  const int swz = ((t >> 3) & 7) << 4;
  const int scol = (colb ^ swz) >> 1;
#pragma unroll
  for (int rr = 0; rr < 2; ++rr) {
    int rho = rr * 64 + (t >> 3);
    int c = ((rho >> 5) << 6) + nh * 32 + (rho & 31);
    async16(B + (size_t)(gcol0 + c) * K_DIM + ktE + scol,
            lds_region + rr * 4096 + t * 8);
  }
}

__device__ __forceinline__ void load_a(const unsigned short* reg_base, int wr,
                                       int fr, int e0, bf16x8 aF[4][2]) {
#pragma unroll
  for (int mi = 0; mi < 4; ++mi) {
    const unsigned short* p = reg_base + (wr * 64 + mi * 16 + fr) * 64;
    aF[mi][0] = *(const bf16x8*)(p + e0);
    aF[mi][1] = *(const bf16x8*)(p + (e0 ^ 32));
  }
}

__device__ __forceinline__ void load_b(const unsigned short* reg_base, int wc,
                                       int fr, int e0, bf16x8 bF[2][2]) {
#pragma unroll
  for (int ni = 0; ni < 2; ++ni) {
    const unsigned short* p = reg_base + (wc * 32 + ni * 16 + fr) * 64;
    bF[ni][0] = *(const bf16x8*)(p + e0);
    bF[ni][1] = *(const bf16x8*)(p + (e0 ^ 32));
  }
}

#define MFMA_QUAD(MH, NH, BF)                                                  \
  do {                                                                         \
    __builtin_amdgcn_s_setprio(1);                                             \
    _Pragma("unroll") for (int kk = 0; kk < 2; ++kk)                           \
    _Pragma("unroll") for (int mi = 0; mi < 4; ++mi)                           \
    _Pragma("unroll") for (int ni = 0; ni < 2; ++ni)                           \
      acc[(MH)*4 + mi][(NH)*2 + ni] = __builtin_amdgcn_mfma_f32_16x16x32_bf16( \
          aF[mi][kk], BF[ni][kk], acc[(MH)*4 + mi][(NH)*2 + ni], 0, 0, 0);     \
    __builtin_amdgcn_s_setprio(0);                                             \
  } while (0)

#define PHASE_SYNC()                                      \
  __builtin_amdgcn_s_barrier();                           \
  asm volatile("s_waitcnt lgkmcnt(0)" ::: "memory")

__global__ void __launch_bounds__(512, 2)
gemm_bt_kernel(const unsigned short* __restrict__ A,  // bf16 [M][K]
               const unsigned short* __restrict__ B,  // bf16 [N][K]
               const float* __restrict__ scale, const float* __restrict__ bias,
               float* __restrict__ C) {
  __shared__ unsigned short lds[65536];  // 128 KiB

  const int t = threadIdx.x;
  const int bid = blockIdx.x;
  const int swz = (bid & 7) * 64 + (bid >> 3);  // 512 wgs, 64/XCD (bijective)
  const int bm = swz >> 4;  // 32 M-tiles
  const int bn = swz & 15;  // 16 N-tiles
  const int brow = bm * 256, bcol = bn * 256;

  const int wid = t >> 6, lane = t & 63;
  const int wr = wid >> 2, wc = wid & 3;
  const int fr = lane & 15, fq = lane >> 4;
  const int e0 = ((fq * 16) ^ ((fr & 7) << 4)) >> 1;  // kk=0 read offset

  f32x4 acc[8][4] = {};
  bf16x8 aF[4][2], bF0[2][2], bF1[2][2];

  // ---- prologue: tile0 all 4 halves + tile1's {A-mh0, B-nh1, A-mh1} ----
  stage_A_half(A, brow, 0, 0, lds + AOFF(0, 0), t);
  stage_B_half(B, bcol, 0, 1, lds + BOFF(0, 1), t);
  stage_A_half(A, brow, 0, 1, lds + AOFF(0, 1), t);
  stage_B_half(B, bcol, 0, 0, lds + BOFF(0, 0), t);
  stage_A_half(A, brow, BK, 0, lds + AOFF(1, 0), t);
  stage_B_half(B, bcol, BK, 1, lds + BOFF(1, 1), t);
  stage_A_half(A, brow, BK, 1, lds + AOFF(1, 1), t);
  asm volatile("s_waitcnt vmcnt(6)" ::: "memory");  // tile0 landed
  __builtin_amdgcn_s_barrier();
  // preload tile0's bF0 (consumed at q0(0) via its lgkmcnt(0))
  load_b(lds + BOFF(0, 0), wc, fr, e0, bF0);

  for (int T = 0; T < NT; ++T) {
    const int b = T & 1;
    const int kN1 = (T + 1) * BK, kN2 = (T + 2) * BK;

    // -- q0 (mh0,nh0): 8 ds_reads (bF0 preloaded at q3(T-1))
    load_a(lds + AOFF(b, 0), wr, fr, e0, aF);
    if (T + 1 < NT) stage_B_half(B, bcol, kN1, 0, lds + BOFF(b ^ 1, 0), t);
    PHASE_SYNC();
    MFMA_QUAD(0, 0, bF0);
    __builtin_amdgcn_s_barrier();

    // -- q1 (mh0,nh1): 4 ds_reads
    load_b(lds + BOFF(b, 1), wc, fr, e0, bF1);
    if (T + 2 < NT) stage_A_half(A, brow, kN2, 0, lds + AOFF(b, 0), t);
    PHASE_SYNC();
    MFMA_QUAD(0, 1, bF1);
    __builtin_amdgcn_s_barrier();

    // -- q2 (mh1,nh1): 8 ds_reads (bF1 reused in regs)
    load_a(lds + AOFF(b, 1), wr, fr, e0, aF);
    if (T + 2 < NT) stage_B_half(B, bcol, kN2, 1, lds + BOFF(b, 1), t);
    PHASE_SYNC();
    MFMA_QUAD(1, 1, bF1);
    if (T < NT - 2)
      asm volatile("s_waitcnt vmcnt(4)" ::: "memory");  // retires <= q0(T) stage
    else if (T == NT - 2)
      asm volatile("s_waitcnt vmcnt(0)" ::: "memory");  // final drain
    __builtin_amdgcn_s_barrier();  // T+1's B-nh0 now visible to all waves

    // -- q3 (mh1,nh0): 0 ds_reads before MFMA; post-MFMA preload of T+1 bF0
    if (T + 2 < NT) stage_A_half(A, brow, kN2, 1, lds + AOFF(b, 1), t);
    PHASE_SYNC();
    MFMA_QUAD(1, 0, bF0);
    if (T + 1 < NT)  // after last use of old bF0 -> same regs, no ping-pong
      load_b(lds + BOFF(b ^ 1, 0), wc, fr, e0, bF0);
    __builtin_amdgcn_s_barrier();
  }

  // ---- epilogue: scale/bias, C/D layout col=lane&15, row=(lane>>4)*4+j ----
#pragma unroll
  for (int n = 0; n < 4; ++n) {
    const int gc = bcol + wc * 64 + n * 16 + fr;
    const float s = scale[gc];
    const float bo = bias[gc];
#pragma unroll
    for (int m = 0; m < 8; ++m) {
      const int gr = brow + wr * 128 + m * 16 + fq * 4;
#pragma unroll
      for (int j = 0; j < 4; ++j)
        C[(size_t)(gr + j) * N_DIM + gc] = acc[m][n][j] * s + bo;
    }
  }
}

// ---------------- naive fallback (only if ws too small) ----------------

__global__ void naive_kernel(const float* __restrict__ x, const int* __restrict__ w,
                             const float* __restrict__ sc, const float* __restrict__ bi,
                             float* __restrict__ out) {
  size_t idx = (size_t)blockIdx.x * blockDim.x + threadIdx.x;
  int m = (int)(idx >> 12);
  int n = (int)(idx & 4095);
  const float* xr = x + (size_t)m * K_DIM;
  const int* wr = w + (size_t)n * K_DIM;
  float acc = 0.f;
  for (int k = 0; k < K_DIM; ++k) acc = fmaf(xr[k], (float)wr[k], acc);
  out[idx] = acc * sc[n] + bi[n];
}

extern "C" void kernel_launch(void* const* d_in, const int* in_sizes, int n_in,
                              void* d_out, int out_size, void* d_ws, size_t ws_size,
                              hipStream_t stream) {
  const float* x = (const float*)d_in[0];
  const int* w = (const int*)d_in[1];
  const float* scale = (const float*)d_in[2];
  const float* bias = (const float*)d_in[3];
  float* out = (float*)d_out;

  const long nx = (long)M_DIM * K_DIM;
  const long nw = (long)N_DIM * K_DIM;
  const size_t need = (size_t)nx * 2 + (size_t)nw * 2;  // 96 MiB

  if (ws_size >= need) {
    unsigned short* xb = (unsigned short*)d_ws;
    unsigned short* wb = xb + nx;
    cvt_x_kernel<<<2048, 256, 0, stream>>>(x, xb, nx);
    cvt_w_kernel<<<2048, 256, 0, stream>>>(w, wb, nw);
    gemm_bt_kernel<<<512, 512, 0, stream>>>(xb, wb, scale, bias, out);
  } else {
    naive_kernel<<<((long)M_DIM * N_DIM) / 256, 256, 0, stream>>>(x, w, scale, bias, out);
  }
}

// Round 5
// 260.802 us; speedup vs baseline: 1.4538x; 1.0342x over previous
//
#include <hip/hip_runtime.h>
#include <hip/hip_bf16.h>

// ---------------------------------------------------------------------------
// EnhancedTernaryLinear: out = (x @ W^T) * scale + bias
// M=8192, N=4096, K=4096. x->bf16, W(ternary)->bf16, then 256x256 MFMA GEMM.
// R5: full-phase fragment read-ahead. Each phase issues next phase's
// ds_read_b128 (inline asm, guaranteed width+order), waits with COUNTED
// lgkmcnt(N)+sched_barrier(0), one barrier per phase (4/tile). LDS service
// hides under the previous phase's MFMA cluster.
// ---------------------------------------------------------------------------

#define M_DIM 8192
#define N_DIM 4096
#define K_DIM 4096
#define BK 64
#define NT (K_DIM / BK)   // 64 K-tiles

typedef __attribute__((ext_vector_type(8))) short bf16x8;
typedef __attribute__((ext_vector_type(4))) float f32x4;

__device__ __forceinline__ unsigned short f2bf(float f) {
  unsigned int u = __float_as_uint(f);
  unsigned int r = (u + 0x7FFFu + ((u >> 16) & 1u)) >> 16;
  return (unsigned short)r;
}

__device__ __forceinline__ void async16(const void* g, void* l) {
  __builtin_amdgcn_global_load_lds(
      (const __attribute__((address_space(1))) void*)g,
      (__attribute__((address_space(3))) void*)l, 16, 0, 0);
}

// ---------------- conversion kernels ----------------

__global__ void cvt_x_kernel(const float* __restrict__ x,
                             unsigned short* __restrict__ xb, long n) {
  long i0 = ((long)blockIdx.x * blockDim.x + threadIdx.x) * 8;
  long stride = (long)gridDim.x * blockDim.x * 8;
  for (long i = i0; i < n; i += stride) {
    float4 v0 = *(const float4*)(x + i);
    float4 v1 = *(const float4*)(x + i + 4);
    bf16x8 o;
    o[0] = (short)f2bf(v0.x); o[1] = (short)f2bf(v0.y);
    o[2] = (short)f2bf(v0.z); o[3] = (short)f2bf(v0.w);
    o[4] = (short)f2bf(v1.x); o[5] = (short)f2bf(v1.y);
    o[6] = (short)f2bf(v1.z); o[7] = (short)f2bf(v1.w);
    *(bf16x8*)(xb + i) = o;
  }
}

__device__ __forceinline__ unsigned short i2bf(int v) {
  return v == 0 ? (unsigned short)0
                : (v > 0 ? (unsigned short)0x3F80 : (unsigned short)0xBF80);
}

__global__ void cvt_w_kernel(const int* __restrict__ w,
                             unsigned short* __restrict__ wb, long n) {
  long i0 = ((long)blockIdx.x * blockDim.x + threadIdx.x) * 8;
  long stride = (long)gridDim.x * blockDim.x * 8;
  for (long i = i0; i < n; i += stride) {
    int4 a = *(const int4*)(w + i);
    int4 b = *(const int4*)(w + i + 4);
    bf16x8 o;
    o[0] = (short)i2bf(a.x); o[1] = (short)i2bf(a.y);
    o[2] = (short)i2bf(a.z); o[3] = (short)i2bf(a.w);
    o[4] = (short)i2bf(b.x); o[5] = (short)i2bf(b.y);
    o[6] = (short)i2bf(b.z); o[7] = (short)i2bf(b.w);
    *(bf16x8*)(wb + i) = o;
  }
}

// ---------------- 256x256 GEMM, 4 phases/K-tile, read-ahead 1 phase -------
// 512 threads = 8 waves (2 wr x 4 wc). Per-wave output 128x64 = 8x4 frags.
// LDS regions (ushort offsets), 128 KiB:
//   A (buf,mh): buf*32768 + mh*8192        (128 rows x 64 cols bf16)
//   B (buf,nh): buf*32768 + 16384 + nh*8192
// Swizzle: LDS[rho][bytecol ^ ((rho&7)<<4)]; staged via inverse-swizzled
// GLOBAL source + linear LDS dest, read with swizzled offset. 0 conflicts.
//
// MFMA usage: q0:(aFx,bF0) q1:(aFx,bF1) q2:(aFy,bF1) q3:(aFy,bF0).
// Reads issued (consumed NEXT phase):  q0: bF1(T) [4]; q1: aFy(T) [8];
//   q2: none; q3: aFx(T+1)+bF0n(T+1) [12].
// Waits before MFMA: q0 lgkm(4), q1 lgkm(8), q2 lgkm(0), q3 lgkm(12).
// Stages (global_load_lds): q0 -> B-nh0(T+1); q1 -> A-mh0(T+2);
//   q2 -> B-nh1(T+2); q3 -> A-mh1(T+2). vmcnt(4) at q2-end retires all of
//   tile T+1's staging (incl. q0(T)'s B-nh0) before q3's reads of it.
// One s_barrier per phase (end). Every stage targets a region whose last
// reads drained at the preceding phase's counted lgkm wait -> WAR safe.

#define AOFF(b, mh) ((b)*32768 + (mh)*8192)
#define BOFF(b, nh) ((b)*32768 + 16384 + (nh)*8192)

__device__ __forceinline__ void stage_A_half(const unsigned short* __restrict__ A,
                                             int grow0, int ktE, int mh,
                                             unsigned short* lds_region, int t) {
  const int colb = (t & 7) * 16;
  const int swz = ((t >> 3) & 7) << 4;
  const int scol = (colb ^ swz) >> 1;
#pragma unroll
  for (int rr = 0; rr < 2; ++rr) {
    int rho = rr * 64 + (t >> 3);
    int r = ((rho >> 6) << 7) + mh * 64 + (rho & 63);
    async16(A + (size_t)(grow0 + r) * K_DIM + ktE + scol,
            lds_region + rr * 4096 + t * 8);
  }
}

__device__ __forceinline__ void stage_B_half(const unsigned short* __restrict__ B,
                                             int gcol0, int ktE, int nh,
                                             unsigned short* lds_region, int t) {
  const int colb = (t & 7) * 16;
  const int swz = ((t >> 3) & 7) << 4;
  const int scol = (colb ^ swz) >> 1;
#pragma unroll
  for (int rr = 0; rr < 2; ++rr) {
    int rho = rr * 64 + (t >> 3);
    int c = ((rho >> 5) << 6) + nh * 32 + (rho & 31);
    async16(B + (size_t)(gcol0 + c) * K_DIM + ktE + scol,
            lds_region + rr * 4096 + t * 8);
  }
}

// Inline-asm ds_read_b128: guaranteed width (lgkm counts depend on it).
#define DSR(dst, base, OFF)                                     \
  asm volatile("ds_read_b128 %0, %1 offset:" OFF                \
               : "=v"(dst) : "v"(base))

__device__ __forceinline__ void rd_a(unsigned b0, bf16x8 aF[4][2]) {
  unsigned b1 = b0 ^ 64;  // kk=1 (byte col ^64, swizzle-compatible)
  DSR(aF[0][0], b0, "0");    DSR(aF[0][1], b1, "0");
  DSR(aF[1][0], b0, "2048"); DSR(aF[1][1], b1, "2048");
  DSR(aF[2][0], b0, "4096"); DSR(aF[2][1], b1, "4096");
  DSR(aF[3][0], b0, "6144"); DSR(aF[3][1], b1, "6144");
}
__device__ __forceinline__ void rd_b(unsigned b0, bf16x8 bF[2][2]) {
  unsigned b1 = b0 ^ 64;
  DSR(bF[0][0], b0, "0");    DSR(bF[0][1], b1, "0");
  DSR(bF[1][0], b0, "2048"); DSR(bF[1][1], b1, "2048");
}

#define LGKM(N)                                                  \
  asm volatile("s_waitcnt lgkmcnt(" #N ")" ::: "memory");        \
  __builtin_amdgcn_sched_barrier(0)
#define VMW(N) asm volatile("s_waitcnt vmcnt(" #N ")" ::: "memory")

#define MFMA16(AF, BF, MH, NH)                                                 \
  do {                                                                         \
    __builtin_amdgcn_s_setprio(1);                                             \
    _Pragma("unroll") for (int kk = 0; kk < 2; ++kk)                           \
    _Pragma("unroll") for (int mi = 0; mi < 4; ++mi)                           \
    _Pragma("unroll") for (int ni = 0; ni < 2; ++ni)                           \
      acc[(MH)*4 + mi][(NH)*2 + ni] = __builtin_amdgcn_mfma_f32_16x16x32_bf16( \
          AF[mi][kk], BF[ni][kk], acc[(MH)*4 + mi][(NH)*2 + ni], 0, 0, 0);     \
    __builtin_amdgcn_s_setprio(0);                                             \
    __builtin_amdgcn_sched_barrier(0);                                         \
  } while (0)

__global__ void __launch_bounds__(512, 2)
gemm_bt_kernel(const unsigned short* __restrict__ A,  // bf16 [M][K]
               const unsigned short* __restrict__ B,  // bf16 [N][K]
               const float* __restrict__ scale, const float* __restrict__ bias,
               float* __restrict__ C) {
  __shared__ unsigned short lds[65536];  // 128 KiB

  const int t = threadIdx.x;
  const int bid = blockIdx.x;
  const int swz = (bid & 7) * 64 + (bid >> 3);  // 512 wgs, 64/XCD (bijective)
  const int bm = swz >> 4;  // 32 M-tiles
  const int bn = swz & 15;  // 16 N-tiles
  const int brow = bm * 256, bcol = bn * 256;

  const int wid = t >> 6, lane = t & 63;
  const int wr = wid >> 2, wc = wid & 3;
  const int fr = lane & 15, fq = lane >> 4;

  // ds_read base addresses (LDS byte offsets; low 32 bits of generic ptr)
  const unsigned ldsb = (unsigned)(unsigned long long)&lds[0];
  const unsigned swzcol = ((unsigned)(fq * 16)) ^ ((unsigned)((fr & 7) << 4));
  const unsigned rcA = ldsb + (unsigned)((wr * 64 + fr) * 128) + swzcol;
  const unsigned rcB = ldsb + (unsigned)((wc * 32 + fr) * 128) + swzcol;

  f32x4 acc[8][4] = {};
  bf16x8 aFx[4][2], aFy[4][2], bF0[2][2], bF1[2][2], bF0n[2][2];

  // ---- prologue: tile0 (4 halves) + tile1 {A-mh0, B-nh1, A-mh1} ----
  stage_A_half(A, brow, 0, 0, lds + AOFF(0, 0), t);
  stage_B_half(B, bcol, 0, 1, lds + BOFF(0, 1), t);
  stage_A_half(A, brow, 0, 1, lds + AOFF(0, 1), t);
  stage_B_half(B, bcol, 0, 0, lds + BOFF(0, 0), t);
  stage_A_half(A, brow, BK, 0, lds + AOFF(1, 0), t);
  stage_B_half(B, bcol, BK, 1, lds + BOFF(1, 1), t);
  stage_A_half(A, brow, BK, 1, lds + AOFF(1, 1), t);
  VMW(6);  // tile0's 8 stage-loads landed
  __builtin_amdgcn_s_barrier();
  // q3(-1) role: read tile0's aFx + bF0 (12 outstanding entering the loop)
  rd_a(rcA + ((unsigned)AOFF(0, 0) << 1), aFx);
  rd_b(rcB + ((unsigned)BOFF(0, 0) << 1), bF0);

  for (int T = 0; T < NT; ++T) {
    const int b = T & 1;

    // -- q0: MFMA(mh0,nh0); issue bF1(T) reads; stage B-nh0(T+1)
    rd_b(rcB + ((unsigned)BOFF(b, 1) << 1), bF1);
    if (T + 1 < NT) stage_B_half(B, bcol, (T + 1) * BK, 0, lds + BOFF(b ^ 1, 0), t);
    LGKM(4);  // aFx + bF0 (issued last phase) drained; own 4 may pend
    MFMA16(aFx, bF0, 0, 0);
    __builtin_amdgcn_s_barrier();

    // -- q1: MFMA(mh0,nh1); issue aFy(T) reads; stage A-mh0(T+2)
    rd_a(rcA + ((unsigned)AOFF(b, 1) << 1), aFy);
    if (T + 2 < NT) stage_A_half(A, brow, (T + 2) * BK, 0, lds + AOFF(b, 0), t);
    LGKM(8);  // bF1 drained; own 8 may pend
    MFMA16(aFx, bF1, 0, 1);
    __builtin_amdgcn_s_barrier();

    // -- q2: MFMA(mh1,nh1); no reads; stage B-nh1(T+2); vmcnt once/tile
    if (T + 2 < NT) stage_B_half(B, bcol, (T + 2) * BK, 1, lds + BOFF(b, 1), t);
    LGKM(0);  // aFy drained (issued a full phase ago -> ~free)
    MFMA16(aFy, bF1, 1, 1);
    if (T < NT - 2)
      VMW(4);  // retires all tile-T+1 staging (outstanding = q1,q2 stages)
    else if (T == NT - 2)
      VMW(0);  // final drain
    __builtin_amdgcn_s_barrier();

    // -- q3: MFMA(mh1,nh0); issue aFx'+bF0'(T+1) reads; stage A-mh1(T+2)
    if (T + 1 < NT) {
      rd_a(rcA + ((unsigned)AOFF(b ^ 1, 0) << 1), aFx);
      rd_b(rcB + ((unsigned)BOFF(b ^ 1, 0) << 1), bF0n);
      if (T + 2 < NT) stage_A_half(A, brow, (T + 2) * BK, 1, lds + AOFF(b, 1), t);
      LGKM(12);  // nothing older outstanding; own 12 may pend
      MFMA16(aFy, bF0, 1, 0);  // uses OLD bF0 (pre-reload SSA values)
#pragma unroll
      for (int ni = 0; ni < 2; ++ni)
#pragma unroll
        for (int kk = 0; kk < 2; ++kk) bF0[ni][kk] = bF0n[ni][kk];
    } else {
      LGKM(0);
      MFMA16(aFy, bF0, 1, 0);
    }
    __builtin_amdgcn_s_barrier();
  }

  // ---- epilogue: scale/bias, C/D layout col=lane&15, row=(lane>>4)*4+j ----
#pragma unroll
  for (int n = 0; n < 4; ++n) {
    const int gc = bcol + wc * 64 + n * 16 + fr;
    const float s = scale[gc];
    const float bo = bias[gc];
#pragma unroll
    for (int m = 0; m < 8; ++m) {
      const int gr = brow + wr * 128 + m * 16 + fq * 4;
#pragma unroll
      for (int j = 0; j < 4; ++j)
        C[(size_t)(gr + j) * N_DIM + gc] = acc[m][n][j] * s + bo;
    }
  }
}

// ---------------- naive fallback (only if ws too small) ----------------

__global__ void naive_kernel(const float* __restrict__ x, const int* __restrict__ w,
                             const float* __restrict__ sc, const float* __restrict__ bi,
                             float* __restrict__ out) {
  size_t idx = (size_t)blockIdx.x * blockDim.x + threadIdx.x;
  int m = (int)(idx >> 12);
  int n = (int)(idx & 4095);
  const float* xr = x + (size_t)m * K_DIM;
  const int* wr = w + (size_t)n * K_DIM;
  float acc = 0.f;
  for (int k = 0; k < K_DIM; ++k) acc = fmaf(xr[k], (float)wr[k], acc);
  out[idx] = acc * sc[n] + bi[n];
}

extern "C" void kernel_launch(void* const* d_in, const int* in_sizes, int n_in,
                              void* d_out, int out_size, void* d_ws, size_t ws_size,
                              hipStream_t stream) {
  const float* x = (const float*)d_in[0];
  const int* w = (const int*)d_in[1];
  const float* scale = (const float*)d_in[2];
  const float* bias = (const float*)d_in[3];
  float* out = (float*)d_out;

  const long nx = (long)M_DIM * K_DIM;
  const long nw = (long)N_DIM * K_DIM;
  const size_t need = (size_t)nx * 2 + (size_t)nw * 2;  // 96 MiB

  if (ws_size >= need) {
    unsigned short* xb = (unsigned short*)d_ws;
    unsigned short* wb = xb + nx;
    cvt_x_kernel<<<2048, 256, 0, stream>>>(x, xb, nx);
    cvt_w_kernel<<<2048, 256, 0, stream>>>(w, wb, nw);
    gemm_bt_kernel<<<512, 512, 0, stream>>>(xb, wb, scale, bias, out);
  } else {
    naive_kernel<<<((long)M_DIM * N_DIM) / 256, 256, 0, stream>>>(x, w, scale, bias, out);
  }
}